// Round 8
// baseline (388.990 us; speedup 1.0000x reference)
//
#include <hip/hip_runtime.h>
#include <hip/hip_bf16.h>

typedef __attribute__((ext_vector_type(8)))  __bf16         bf16x8;
typedef __attribute__((ext_vector_type(4)))  float          f32x4;
typedef __attribute__((ext_vector_type(8)))  unsigned short u16x8;

#define LOG2E 1.44269504088896340736f

#if __has_builtin(__builtin_amdgcn_exp2f)
#define EXP2F(x) __builtin_amdgcn_exp2f(x)
#else
#define EXP2F(x) __builtin_exp2f(x)
#endif

__device__ __forceinline__ unsigned short f2b(float f) {
  union { __bf16 h; unsigned short s; } o; o.h = (__bf16)f; return o.s;
}

// ---------------- kernel 1: h = x@W fp32 (VALU); hT bf16, s1', s2' ----------
// grid 512 x 256 thr; block = 16 rows. W staged in LDS in two 64-row halves.
__global__ __launch_bounds__(256) void k_prep(
    const float* __restrict__ x, const float* __restrict__ W,
    const float* __restrict__ a1, const float* __restrict__ a2,
    const float* __restrict__ ab,
    unsigned short* __restrict__ hT, float* __restrict__ s1p,
    float* __restrict__ s2p) {
  __shared__ __align__(16) float Ws[64 * 128];   // 32 KB (one K-half of W)
  __shared__ __align__(16) float Xs[16 * 128];   // 8 KB
  const int t = threadIdx.x;
  const int rb = blockIdx.x * 16;
  const int r  = t >> 4;    // row 0..15
  const int fg = t & 15;    // feature octet 0..15

  {
    int off = t * 8;
    *(f32x4*)(Xs + off)     = *(const f32x4*)(x + (long)rb * 128 + off);
    *(f32x4*)(Xs + off + 4) = *(const f32x4*)(x + (long)rb * 128 + off + 4);
  }

  float acc[8];
#pragma unroll
  for (int j = 0; j < 8; ++j) acc[j] = 0.f;

  for (int half = 0; half < 2; ++half) {
    __syncthreads();
#pragma unroll
    for (int c = 0; c < 8; ++c) {
      int off = c * 1024 + t * 4;
      *(f32x4*)(Ws + off) = *(const f32x4*)(W + half * 8192 + off);
    }
    __syncthreads();
    for (int k = 0; k < 64; ++k) {
      float xv = Xs[r * 128 + half * 64 + k];
      f32x4 w0 = *(const f32x4*)(Ws + k * 128 + fg * 8);
      f32x4 w1 = *(const f32x4*)(Ws + k * 128 + fg * 8 + 4);
#pragma unroll
      for (int j = 0; j < 4; ++j) {
        acc[j]     += xv * w0[j];
        acc[4 + j] += xv * w1[j];
      }
    }
  }

  float p1 = 0.f, p2 = 0.f;
#pragma unroll
  for (int j = 0; j < 8; ++j) {
    p1 += acc[j] * a1[fg * 8 + j];
    p2 += acc[j] * a2[fg * 8 + j];
  }
#pragma unroll
  for (int mask = 1; mask <= 8; mask <<= 1) {
    p1 += __shfl_xor(p1, mask, 64);
    p2 += __shfl_xor(p2, mask, 64);
  }
  if (fg == 0) {
    s1p[rb + r] = LOG2E * (p1 + ab[0]);   // exp2-domain, bias folded
    s2p[rb + r] = LOG2E * p2;
  }
#pragma unroll
  for (int j = 0; j < 8; ++j)
    hT[(long)(fg * 8 + j) * 8192 + rb + r] = f2b(acc[j]);
}

// ---------------- kernel 2: fused mask+softmax+GEMM, full-K, fp32 out ------
// grid 256 x 512 thr (8 waves). Block = 32 rows x 8192 j x 128 f.
// m89-verified mfma_f32_16x16x32_bf16; A/B-verified vs pure-VALU twin (r4==r5).
__global__ __launch_bounds__(512, 2) void k_attn(
    const float* __restrict__ adj, const unsigned short* __restrict__ hT,
    const float* __restrict__ s1p, const float* __restrict__ s2p,
    float* __restrict__ out) {
  __shared__ __align__(16) unsigned short Bs[128 * 128];  // hT k-tile, XOR-swizzled
  __shared__ __align__(16) unsigned short As[32 * 136];   // w tile, +8 pad/row
  __shared__ float dens[32];

  const int t = threadIdx.x;
  const int i0 = blockIdx.x * 32;
  const int lane = t & 63;
  const int wv = t >> 6;          // 0..7
  const int r  = t >> 4;          // 0..31: adj/As row, Bs staging row-group
  const int kc = t & 15;          // 0..15: 8-col chunk / staging slot
  const int m    = lane & 15;
  const int quad = lane >> 4;     // 0..3
  const int rt = wv & 1;          // row tile
  const int f0 = (wv >> 1) * 32;  // feature base

  const float s1v = s1p[i0 + r];
  const float* adjp = adj + (long)(i0 + r) * 8192 + kc * 8;
  const float* s2pp = s2p + kc * 8;

  f32x4 acc0, acc1;
#pragma unroll
  for (int p = 0; p < 4; ++p) { acc0[p] = 0.f; acc1[p] = 0.f; }
  float den = 0.f;

  // prologue: iter-0 adj/s2 + hT tile
  f32x4 ar0 = __builtin_nontemporal_load((const f32x4*)(adjp));
  f32x4 ar1 = __builtin_nontemporal_load((const f32x4*)(adjp + 4));
  f32x4 cs0 = *(const f32x4*)(s2pp);
  f32x4 cs1 = *(const f32x4*)(s2pp + 4);
  u16x8 stg[4];
#pragma unroll
  for (int rr = 0; rr < 4; ++rr) {
    int f = rr * 32 + r;
    int cg = kc ^ (f & 7);
    stg[rr] = *(const u16x8*)(hT + (long)f * 8192 + cg * 8);
  }

  for (int it = 0; it < 64; ++it) {
    // ---- staged hT regs -> Bs (global chunk cg sits at slot kc) ----
#pragma unroll
    for (int rr = 0; rr < 4; ++rr) {
      int f = rr * 32 + r;
      *(u16x8*)(Bs + f * 128 + kc * 8) = stg[rr];
    }
    // ---- prefetch next adj/s2 ----
    const int itn = (it + 1) & 63;
    f32x4 nr0 = __builtin_nontemporal_load((const f32x4*)(adjp + (long)itn * 128));
    f32x4 nr1 = __builtin_nontemporal_load((const f32x4*)(adjp + (long)itn * 128 + 4));
    f32x4 ns0 = *(const f32x4*)(s2pp + itn * 128);
    f32x4 ns1 = *(const f32x4*)(s2pp + itn * 128 + 4);

    // ---- w = adj * exp2(leaky(t')) for this thread's 8 columns ----
    u16x8 w;
    float dloc = 0.f;
#pragma unroll
    for (int j = 0; j < 4; ++j) {
      float tp = s1v + cs0[j];
      float wval = ar0[j] * EXP2F(fmaxf(tp, 0.2f * tp));
      dloc += wval; w[j] = f2b(wval);
    }
#pragma unroll
    for (int j = 0; j < 4; ++j) {
      float tp = s1v + cs1[j];
      float wval = ar1[j] * EXP2F(fmaxf(tp, 0.2f * tp));
      dloc += wval; w[4 + j] = f2b(wval);
    }
    den += dloc;
    *(u16x8*)(As + r * 136 + kc * 8) = w;

    __syncthreads();   // As/Bs visible to all waves

    // ---- prefetch next hT tile (latency hides under MFMA) ----
    if (it < 63) {
      const unsigned short* hTi = hT + (long)(it + 1) * 128;
#pragma unroll
      for (int rr = 0; rr < 4; ++rr) {
        int f = rr * 32 + r;
        int cg = kc ^ (f & 7);
        stg[rr] = *(const u16x8*)(hTi + (long)f * 8192 + cg * 8);
      }
    }

    // ---- 8x mfma_f32_16x16x32_bf16 (2 feature tiles x 4 K-steps) ----
#pragma unroll
    for (int ks = 0; ks < 4; ++ks) {
      bf16x8 af = *(const bf16x8*)(As + (rt * 16 + m) * 136 + ks * 32 + quad * 8);
      int c = ks * 4 + quad;
      {
        int f = f0 + m;
        int slot = c ^ (f & 7);
        bf16x8 bv = *(const bf16x8*)(Bs + f * 128 + slot * 8);
        acc0 = __builtin_amdgcn_mfma_f32_16x16x32_bf16(af, bv, acc0, 0, 0, 0);
      }
      {
        int f = f0 + 16 + m;
        int slot = c ^ (f & 7);
        bf16x8 bv = *(const bf16x8*)(Bs + f * 128 + slot * 8);
        acc1 = __builtin_amdgcn_mfma_f32_16x16x32_bf16(af, bv, acc1, 0, 0, 0);
      }
    }
    __syncthreads();   // reads done before next iter's stores

    ar0 = nr0; ar1 = nr1; cs0 = ns0; cs1 = ns1;
  }

  // ---- full-row denominator: reduce over kc (lane low4), share via LDS ----
  den += __shfl_xor(den, 1, 64);
  den += __shfl_xor(den, 2, 64);
  den += __shfl_xor(den, 4, 64);
  den += __shfl_xor(den, 8, 64);
  if (kc == 0) dens[r] = den;
  __syncthreads();

  // ---- divide + fp32 store. C layout (16x16): col=lane&15, row=quad*4+reg --
#pragma unroll
  for (int p = 0; p < 4; ++p) {
    int row = rt * 16 + quad * 4 + p;
    float d = dens[row];
    float inv = (d != 0.f) ? (1.f / d) : 0.f;
    out[(long)(i0 + row) * 128 + f0 + m]      = acc0[p] * inv;
    out[(long)(i0 + row) * 128 + f0 + 16 + m] = acc1[p] * inv;
  }
}

extern "C" void kernel_launch(void* const* d_in, const int* in_sizes, int n_in,
                              void* d_out, int out_size, void* d_ws, size_t ws_size,
                              hipStream_t stream) {
  // size-based input dispatch (a1/a2 keep their relative order)
  int ix = 0, iadj = 1, iw = 2, ia1 = 3, ia2 = 4, iab = 5;
  {
    int f128[2] = {-1, -1};
    int tx = -1, tadj = -1, tw = -1, tab = -1, n128 = 0;
    for (int i = 0; i < n_in; ++i) {
      int s = in_sizes[i];
      if (s == 67108864) tadj = i;
      else if (s == 1048576) tx = i;
      else if (s == 16384) tw = i;
      else if (s == 128 && n128 < 2) f128[n128++] = i;
      else if (s == 1) tab = i;
    }
    if (tx >= 0 && tadj >= 0 && tw >= 0 && tab >= 0 && n128 == 2) {
      ix = tx; iadj = tadj; iw = tw; ia1 = f128[0]; ia2 = f128[1]; iab = tab;
    }
  }
  const float* x   = (const float*)d_in[ix];
  const float* adj = (const float*)d_in[iadj];
  const float* W   = (const float*)d_in[iw];
  const float* a1  = (const float*)d_in[ia1];
  const float* a2  = (const float*)d_in[ia2];
  const float* ab  = (const float*)d_in[iab];

  char* ws = (char*)d_ws;
  unsigned short* hT = (unsigned short*)(ws);           // 2 MB  bf16 h^T [128][8192]
  float* s1p = (float*)(ws + 2097152);                  // 32 KB
  float* s2p = (float*)(ws + 2097152 + 32768);          // 32 KB

  k_prep<<<dim3(512), dim3(256), 0, stream>>>(x, W, a1, a2, ab, hT, s1p, s2p);
  k_attn<<<dim3(256), dim3(512), 0, stream>>>(adj, hT, s1p, s2p, (float*)d_out);
}